// Round 1
// baseline (456.549 us; speedup 1.0000x reference)
//
#include <hip/hip_runtime.h>

#define SEQ   2048
#define EMBD  1024
#define HEADS 16
#define HDIM  64
#define MTOT  8192

typedef __attribute__((ext_vector_type(8))) _Float16 half8;
typedef __attribute__((ext_vector_type(4))) float f32x4;

__device__ __forceinline__ f32x4 mfma16(half8 a, half8 b, f32x4 c) {
  return __builtin_amdgcn_mfma_f32_16x16x32_f16(a, b, c, 0, 0, 0);
}

__device__ __forceinline__ void gload_lds16(const void* g, void* l) {
  __builtin_amdgcn_global_load_lds(
      (const __attribute__((address_space(1))) unsigned int*)g,
      (__attribute__((address_space(3))) unsigned int*)l, 16, 0, 0);
}

// ---------------- cast fp32 -> fp16, 8 elems/thread ----------------
__global__ void k_cvt(const float* __restrict__ in, _Float16* __restrict__ out) {
  size_t i = (size_t)blockIdx.x * blockDim.x + threadIdx.x;
  const f32x4* in4 = (const f32x4*)in;
  f32x4 a = in4[2 * i], b = in4[2 * i + 1];
  half8 h;
  h[0] = (_Float16)a[0]; h[1] = (_Float16)a[1];
  h[2] = (_Float16)a[2]; h[3] = (_Float16)a[3];
  h[4] = (_Float16)b[0]; h[5] = (_Float16)b[1];
  h[6] = (_Float16)b[2]; h[7] = (_Float16)b[3];
  *(half8*)(out + i * 8) = h;
}

// ------------- transpose fp32 [R][C] -> fp16 [C][R] -------------
__global__ void k_transpose(const float* __restrict__ in, _Float16* __restrict__ out,
                            int R, int C) {
  int col = blockIdx.x * 256 + threadIdx.x;
  int r0 = blockIdx.y * 256;
  #pragma unroll 4
  for (int r = 0; r < 256; ++r) {
    out[(size_t)col * R + r0 + r] = (_Float16)in[(size_t)(r0 + r) * C + col];
  }
}

// ------- GEMM: C[M,N] = A[M,1024] @ Bt[N,1024]^T + bias -------
// 128x128 tile, BK=64, 4 waves of 64x64, global_load_lds staging.
// EPI 0: scatter f16 to q/k (row-major per head) and vt (transposed per head).
// EPI 1: fp32 + bias to outf.
template<int EPI>
__global__ __launch_bounds__(256) void k_gemm(
    const _Float16* __restrict__ A, const _Float16* __restrict__ Bt,
    const float* __restrict__ bias, float* __restrict__ outf,
    _Float16* __restrict__ q, _Float16* __restrict__ k, _Float16* __restrict__ vt)
{
  __shared__ _Float16 sm[2 * 128 * 64];
  _Float16* sA = sm;
  _Float16* sB = sm + 128 * 64;
  const int tid = threadIdx.x;
  const int l = tid & 63, g = l >> 4, c = l & 15;
  const int w = tid >> 6;
  const int wm = (w >> 1) * 64, wn = (w & 1) * 64;
  const int rowBase = blockIdx.y * 128;
  const int colBase = blockIdx.x * 128;

  f32x4 acc[4][4] = {};

  const _Float16* Ag = A + (size_t)(rowBase + (tid >> 3)) * 1024 + (tid & 7) * 8;
  const _Float16* Bg = Bt + (size_t)(colBase + (tid >> 3)) * 1024 + (tid & 7) * 8;
  _Float16* la = sA + tid * 8;
  _Float16* lb = sB + tid * 8;

  for (int kt = 0; kt < 16; ++kt) {
    const _Float16* ag = Ag + kt * 64;
    const _Float16* bg = Bg + kt * 64;
    #pragma unroll
    for (int i = 0; i < 4; ++i) {
      gload_lds16(ag + (size_t)i * 32 * 1024, la + i * 256 * 8);
      gload_lds16(bg + (size_t)i * 32 * 1024, lb + i * 256 * 8);
    }
    __syncthreads();
    #pragma unroll
    for (int kk = 0; kk < 2; ++kk) {
      half8 af[4], bf[4];
      #pragma unroll
      for (int t = 0; t < 4; ++t)
        af[t] = *(const half8*)(sA + (wm + t * 16 + c) * 64 + kk * 32 + g * 8);
      #pragma unroll
      for (int t = 0; t < 4; ++t)
        bf[t] = *(const half8*)(sB + (wn + t * 16 + c) * 64 + kk * 32 + g * 8);
      #pragma unroll
      for (int mt = 0; mt < 4; ++mt)
        #pragma unroll
        for (int nt = 0; nt < 4; ++nt)
          acc[mt][nt] = mfma16(af[mt], bf[nt], acc[mt][nt]);
    }
    __syncthreads();
  }

  #pragma unroll
  for (int mt = 0; mt < 4; ++mt) {
    #pragma unroll
    for (int nt = 0; nt < 4; ++nt) {
      const int col = colBase + wn + nt * 16 + c;
      const float bv = bias[col];
      #pragma unroll
      for (int r = 0; r < 4; ++r) {
        const int row = rowBase + wm + mt * 16 + g * 4 + r;
        const float val = acc[mt][nt][r] + bv;
        if constexpr (EPI == 0) {
          const int s = col >> 10, h = (col >> 6) & 15, d = col & 63;
          const int b = row >> 11, n = row & 2047;
          const int bh = b * HEADS + h;
          const _Float16 hv = (_Float16)val;
          if (s == 2)      vt[((size_t)bh * HDIM + d) * SEQ + n] = hv;
          else if (s == 1) k [((size_t)bh * SEQ + n) * HDIM + d] = hv;
          else             q [((size_t)bh * SEQ + n) * HDIM + d] = hv;
        } else {
          outf[(size_t)row * EMBD + col] = val;
        }
      }
    }
  }
}

// ---------------- flash attention fwd ----------------
// grid (SEQ/128, B*H). 4 waves x 32 q-rows. KB=64 keys/iter.
// LDS rows padded to 72 halves (144B) -> bank-balanced ds_read_b128.
__global__ __launch_bounds__(256) void k_attn(
    const _Float16* __restrict__ q, const _Float16* __restrict__ kg,
    const _Float16* __restrict__ vt, _Float16* __restrict__ aout)
{
  __shared__ _Float16 sm[(2 * 64 + 4 * 32) * 72];
  _Float16* Ks = sm;
  _Float16* Vs = sm + 64 * 72;
  const int tid = threadIdx.x;
  const int w = tid >> 6, l = tid & 63, g = l >> 4, c = l & 15;
  _Float16* Pw = sm + 2 * 64 * 72 + w * 32 * 72;
  const int bh = blockIdx.y;
  const int n0 = blockIdx.x * 128 + w * 32;
  const _Float16* qb = q  + (size_t)bh * SEQ * HDIM;
  const _Float16* kb = kg + (size_t)bh * SEQ * HDIM;
  const _Float16* vb = vt + (size_t)bh * HDIM * SEQ;

  half8 aq[2][2];
  #pragma unroll
  for (int mt = 0; mt < 2; ++mt)
    #pragma unroll
    for (int kk = 0; kk < 2; ++kk)
      aq[mt][kk] = *(const half8*)(qb + (size_t)(n0 + mt * 16 + c) * HDIM + kk * 32 + g * 8);

  float m_[2][4], l_[2][4];
  f32x4 o[2][4] = {};
  #pragma unroll
  for (int mt = 0; mt < 2; ++mt)
    #pragma unroll
    for (int r = 0; r < 4; ++r) { m_[mt][r] = -1e30f; l_[mt][r] = 0.f; }

  for (int kt = 0; kt < SEQ / 64; ++kt) {
    const _Float16* ks = kb + (size_t)kt * 64 * HDIM;
    #pragma unroll
    for (int i = 0; i < 2; ++i) {
      const int idx = i * 256 + tid;
      const int row = idx >> 3, cb = idx & 7;
      *(half8*)(Ks + row * 72 + cb * 8) = *(const half8*)(ks + (size_t)idx * 8);
      *(half8*)(Vs + row * 72 + cb * 8) =
          *(const half8*)(vb + (size_t)row * SEQ + kt * 64 + cb * 8);
    }
    __syncthreads();

    f32x4 s[2][4] = {};
    #pragma unroll
    for (int kk = 0; kk < 2; ++kk) {
      #pragma unroll
      for (int jt = 0; jt < 4; ++jt) {
        half8 bk = *(const half8*)(Ks + (jt * 16 + c) * 72 + kk * 32 + g * 8);
        s[0][jt] = mfma16(aq[0][kk], bk, s[0][jt]);
        s[1][jt] = mfma16(aq[1][kk], bk, s[1][jt]);
      }
    }

    #pragma unroll
    for (int mt = 0; mt < 2; ++mt) {
      #pragma unroll
      for (int r = 0; r < 4; ++r) {
        float s0 = s[mt][0][r] * 0.125f;
        float s1 = s[mt][1][r] * 0.125f;
        float s2 = s[mt][2][r] * 0.125f;
        float s3 = s[mt][3][r] * 0.125f;
        float mx = fmaxf(fmaxf(s0, s1), fmaxf(s2, s3));
        #pragma unroll
        for (int msk = 1; msk < 16; msk <<= 1)
          mx = fmaxf(mx, __shfl_xor(mx, msk, 64));
        const float mold = m_[mt][r];
        const float mn = fmaxf(mold, mx);
        const float cor = __builtin_amdgcn_exp2f((mold - mn) * 1.44269504f);
        float p0 = __builtin_amdgcn_exp2f((s0 - mn) * 1.44269504f);
        float p1 = __builtin_amdgcn_exp2f((s1 - mn) * 1.44269504f);
        float p2 = __builtin_amdgcn_exp2f((s2 - mn) * 1.44269504f);
        float p3 = __builtin_amdgcn_exp2f((s3 - mn) * 1.44269504f);
        float rs = (p0 + p1) + (p2 + p3);
        #pragma unroll
        for (int msk = 1; msk < 16; msk <<= 1)
          rs += __shfl_xor(rs, msk, 64);
        m_[mt][r] = mn;
        l_[mt][r] = l_[mt][r] * cor + rs;
        o[mt][0][r] *= cor; o[mt][1][r] *= cor;
        o[mt][2][r] *= cor; o[mt][3][r] *= cor;
        _Float16* pr = Pw + (mt * 16 + g * 4 + r) * 72 + c;
        pr[0]  = (_Float16)p0;
        pr[16] = (_Float16)p1;
        pr[32] = (_Float16)p2;
        pr[48] = (_Float16)p3;
      }
    }

    #pragma unroll
    for (int kk = 0; kk < 2; ++kk) {
      half8 ap0 = *(const half8*)(Pw + (0  + c) * 72 + kk * 32 + g * 8);
      half8 ap1 = *(const half8*)(Pw + (16 + c) * 72 + kk * 32 + g * 8);
      #pragma unroll
      for (int dt = 0; dt < 4; ++dt) {
        half8 bv = *(const half8*)(Vs + (dt * 16 + c) * 72 + kk * 32 + g * 8);
        o[0][dt] = mfma16(ap0, bv, o[0][dt]);
        o[1][dt] = mfma16(ap1, bv, o[1][dt]);
      }
    }
    __syncthreads();
  }

  const int b = bh >> 4, h = bh & 15;
  #pragma unroll
  for (int mt = 0; mt < 2; ++mt) {
    #pragma unroll
    for (int r = 0; r < 4; ++r) {
      const float rl = __builtin_amdgcn_rcpf(l_[mt][r]);
      const int n = n0 + mt * 16 + g * 4 + r;
      #pragma unroll
      for (int dt = 0; dt < 4; ++dt) {
        aout[((size_t)(b * SEQ + n)) * EMBD + h * HDIM + dt * 16 + c] =
            (_Float16)(o[mt][dt][r] * rl);
      }
    }
  }
}

extern "C" void kernel_launch(void* const* d_in, const int* in_sizes, int n_in,
                              void* d_out, int out_size, void* d_ws, size_t ws_size,
                              hipStream_t stream) {
  const float* x    = (const float*)d_in[0];
  const float* Wqkv = (const float*)d_in[1];
  const float* bqkv = (const float*)d_in[2];
  const float* Wout = (const float*)d_in[3];
  const float* bout = (const float*)d_in[4];
  float* out = (float*)d_out;

  // workspace layout (halves). aout reuses xh (dead after QKV GEMM).
  _Float16* ws    = (_Float16*)d_ws;
  _Float16* xh    = ws;                                   // 8M
  _Float16* wqkvt = xh + (size_t)MTOT * EMBD;             // 3M
  _Float16* woutt = wqkvt + (size_t)3 * EMBD * EMBD;      // 1M
  _Float16* qbuf  = woutt + (size_t)EMBD * EMBD;          // 8M
  _Float16* kbuf  = qbuf + (size_t)MTOT * EMBD;           // 8M
  _Float16* vtbuf = kbuf + (size_t)MTOT * EMBD;           // 8M
  _Float16* aout  = xh;

  k_cvt<<<4096, 256, 0, stream>>>(x, xh);
  k_transpose<<<dim3(12, 4), 256, 0, stream>>>(Wqkv, wqkvt, 1024, 3072);
  k_transpose<<<dim3(4, 4), 256, 0, stream>>>(Wout, woutt, 1024, 1024);
  k_gemm<0><<<dim3(24, 64), 256, 0, stream>>>(xh, wqkvt, bqkv, nullptr,
                                              qbuf, kbuf, vtbuf);
  k_attn<<<dim3(SEQ / 128, 64), 256, 0, stream>>>(qbuf, kbuf, vtbuf, aout);
  k_gemm<1><<<dim3(8, 64), 256, 0, stream>>>(aout, woutt, bout, out,
                                             nullptr, nullptr, nullptr);
}

// Round 2
// 266.572 us; speedup vs baseline: 1.7127x; 1.7127x over previous
//
#include <hip/hip_runtime.h>

#define SEQ   2048
#define EMBD  1024
#define HEADS 16
#define HDIM  64
#define MTOT  8192

typedef __attribute__((ext_vector_type(8))) _Float16 half8;
typedef __attribute__((ext_vector_type(4))) _Float16 half4;
typedef __attribute__((ext_vector_type(4))) float f32x4;

__device__ __forceinline__ f32x4 mfma16(half8 a, half8 b, f32x4 c) {
  return __builtin_amdgcn_mfma_f32_16x16x32_f16(a, b, c, 0, 0, 0);
}

__device__ __forceinline__ void gload_lds16(const void* g, void* l) {
  __builtin_amdgcn_global_load_lds(
      (const __attribute__((address_space(1))) unsigned int*)g,
      (__attribute__((address_space(3))) unsigned int*)l, 16, 0, 0);
}

// ---------------- cast fp32 -> fp16, 8 elems/thread ----------------
__global__ void k_cvt(const float* __restrict__ in, _Float16* __restrict__ out) {
  size_t i = (size_t)blockIdx.x * blockDim.x + threadIdx.x;
  const f32x4* in4 = (const f32x4*)in;
  f32x4 a = in4[2 * i], b = in4[2 * i + 1];
  half8 h;
  h[0] = (_Float16)a[0]; h[1] = (_Float16)a[1];
  h[2] = (_Float16)a[2]; h[3] = (_Float16)a[3];
  h[4] = (_Float16)b[0]; h[5] = (_Float16)b[1];
  h[6] = (_Float16)b[2]; h[7] = (_Float16)b[3];
  *(half8*)(out + i * 8) = h;
}

// ------- LDS-tiled transpose fp32 [R][C] -> fp16 [C][R], 64x64 tiles -------
__global__ __launch_bounds__(256) void k_transpose(const float* __restrict__ in,
                                                   _Float16* __restrict__ out,
                                                   int R, int C) {
  __shared__ _Float16 tile[64][65];
  const int tid = threadIdx.x;
  const int r0 = blockIdx.y * 64, c0 = blockIdx.x * 64;
  const int tr = tid >> 6;   // 0..3
  const int tc = tid & 63;
  #pragma unroll
  for (int i = 0; i < 16; ++i) {
    const int r = i * 4 + tr;
    tile[r][tc] = (_Float16)in[(size_t)(r0 + r) * C + c0 + tc];
  }
  __syncthreads();
  #pragma unroll
  for (int i = 0; i < 16; ++i) {
    const int cc = i * 4 + tr;            // column of in = row of out
    out[(size_t)(c0 + cc) * R + r0 + tc] = tile[tc][cc];  // coalesced in tc
  }
}

// ------- GEMM: C[M,N] = A[M,1024] @ Bt[N,1024]^T + bias -------
// 128x128 tile, BK=64, 4 waves of 64x64, global_load_lds staging.
// EPI 0: scatter f16 to q/k (row-major per head) and vt (transposed per head).
// EPI 1: fp32 + bias to outf.
template<int EPI>
__global__ __launch_bounds__(256) void k_gemm(
    const _Float16* __restrict__ A, const _Float16* __restrict__ Bt,
    const float* __restrict__ bias, float* __restrict__ outf,
    _Float16* __restrict__ q, _Float16* __restrict__ k, _Float16* __restrict__ vt)
{
  __shared__ _Float16 sm[2 * 128 * 64];
  _Float16* sA = sm;
  _Float16* sB = sm + 128 * 64;
  const int tid = threadIdx.x;
  const int l = tid & 63, g = l >> 4, c = l & 15;
  const int w = tid >> 6;
  const int wm = (w >> 1) * 64, wn = (w & 1) * 64;
  const int rowBase = blockIdx.y * 128;
  const int colBase = blockIdx.x * 128;

  f32x4 acc[4][4] = {};

  const _Float16* Ag = A + (size_t)(rowBase + (tid >> 3)) * 1024 + (tid & 7) * 8;
  const _Float16* Bg = Bt + (size_t)(colBase + (tid >> 3)) * 1024 + (tid & 7) * 8;
  _Float16* la = sA + tid * 8;
  _Float16* lb = sB + tid * 8;

  for (int kt = 0; kt < 16; ++kt) {
    const _Float16* ag = Ag + kt * 64;
    const _Float16* bg = Bg + kt * 64;
    #pragma unroll
    for (int i = 0; i < 4; ++i) {
      gload_lds16(ag + (size_t)i * 32 * 1024, la + i * 256 * 8);
      gload_lds16(bg + (size_t)i * 32 * 1024, lb + i * 256 * 8);
    }
    __syncthreads();
    #pragma unroll
    for (int kk = 0; kk < 2; ++kk) {
      half8 af[4], bf[4];
      #pragma unroll
      for (int t = 0; t < 4; ++t)
        af[t] = *(const half8*)(sA + (wm + t * 16 + c) * 64 + kk * 32 + g * 8);
      #pragma unroll
      for (int t = 0; t < 4; ++t)
        bf[t] = *(const half8*)(sB + (wn + t * 16 + c) * 64 + kk * 32 + g * 8);
      #pragma unroll
      for (int mt = 0; mt < 4; ++mt)
        #pragma unroll
        for (int nt = 0; nt < 4; ++nt)
          acc[mt][nt] = mfma16(af[mt], bf[nt], acc[mt][nt]);
    }
    __syncthreads();
  }

  #pragma unroll
  for (int mt = 0; mt < 4; ++mt) {
    #pragma unroll
    for (int nt = 0; nt < 4; ++nt) {
      const int col = colBase + wn + nt * 16 + c;
      const float bv = bias[col];
      #pragma unroll
      for (int r = 0; r < 4; ++r) {
        const int row = rowBase + wm + mt * 16 + g * 4 + r;
        const float val = acc[mt][nt][r] + bv;
        if constexpr (EPI == 0) {
          const int s = col >> 10, h = (col >> 6) & 15, d = col & 63;
          const int b = row >> 11, n = row & 2047;
          const int bh = b * HEADS + h;
          const _Float16 hv = (_Float16)val;
          if (s == 2)      vt[((size_t)bh * HDIM + d) * SEQ + n] = hv;
          else if (s == 1) k [((size_t)bh * SEQ + n) * HDIM + d] = hv;
          else             q [((size_t)bh * SEQ + n) * HDIM + d] = hv;
        } else {
          outf[(size_t)row * EMBD + col] = val;
        }
      }
    }
  }
}

// ---------------- flash attention fwd (swapped QK^T, in-register softmax) ----
// grid (SEQ/128, B*H). 4 waves x 32 q-rows. KB=64 keys/iter.
// S^T = mfma(K, Q): lane (g,c) holds S[q = qf*16+c][k = kt4*16+g*4+r] -> the
// full 64-key row lives in 4 lanes (g=0..3) => softmax = local reduce + 2 shfl.
__global__ __launch_bounds__(256) void k_attn(
    const _Float16* __restrict__ q, const _Float16* __restrict__ kg,
    const _Float16* __restrict__ vt, _Float16* __restrict__ aout)
{
  __shared__ _Float16 sm[(64 + 64 + 4 * 32) * 72];
  _Float16* Ks = sm;                       // [64 keys][72] rows = K[key][d]
  _Float16* Vs = sm + 64 * 72;             // [64 d][72]    rows = V^T[d][key]
  const int tid = threadIdx.x;
  const int w = tid >> 6, l = tid & 63, g = l >> 4, c = l & 15;
  _Float16* Pw = sm + 2 * 64 * 72 + w * 32 * 72;   // per-wave P[q 0..31][72]
  const int bh = blockIdx.y;
  const int n0 = blockIdx.x * 128 + w * 32;
  const _Float16* qb = q  + (size_t)bh * SEQ * HDIM;
  const _Float16* kb = kg + (size_t)bh * SEQ * HDIM;
  const _Float16* vb = vt + (size_t)bh * HDIM * SEQ;

  // Q fragments (B operand), prescaled by 1/sqrt(64) = 1/8 (exact in f16)
  half8 aq[2][2];
  #pragma unroll
  for (int qt = 0; qt < 2; ++qt)
    #pragma unroll
    for (int kk = 0; kk < 2; ++kk) {
      half8 t = *(const half8*)(qb + (size_t)(n0 + qt * 16 + c) * HDIM + kk * 32 + g * 8);
      aq[qt][kk] = t * (_Float16)0.125f;
    }

  float m_[2] = {-1e30f, -1e30f};   // running max for q = qf*16 + c
  float l_[2] = {0.f, 0.f};
  f32x4 o[2][4] = {};

  for (int kt = 0; kt < SEQ / 64; ++kt) {
    const _Float16* ks = kb + (size_t)kt * 64 * HDIM;
    #pragma unroll
    for (int i = 0; i < 2; ++i) {
      const int idx = i * 256 + tid;
      const int row = idx >> 3, cb = idx & 7;
      *(half8*)(Ks + row * 72 + cb * 8) = *(const half8*)(ks + (size_t)idx * 8);
      *(half8*)(Vs + row * 72 + cb * 8) =
          *(const half8*)(vb + (size_t)row * SEQ + kt * 64 + cb * 8);
    }
    __syncthreads();

    // S^T[k][q]: s[kt4][qf], lane (g,c): k = kt4*16+g*4+r, q = qf*16+c
    f32x4 s[4][2] = {};
    #pragma unroll
    for (int kk = 0; kk < 2; ++kk) {
      #pragma unroll
      for (int kt4 = 0; kt4 < 4; ++kt4) {
        half8 ak = *(const half8*)(Ks + (kt4 * 16 + c) * 72 + kk * 32 + g * 8);
        s[kt4][0] = mfma16(ak, aq[0][kk], s[kt4][0]);
        s[kt4][1] = mfma16(ak, aq[1][kk], s[kt4][1]);
      }
    }

    #pragma unroll
    for (int qf = 0; qf < 2; ++qf) {
      // row max: 16 local values + reduce over the 4 g-lanes
      float mx = s[0][qf][0];
      #pragma unroll
      for (int kt4 = 0; kt4 < 4; ++kt4)
        #pragma unroll
        for (int r = 0; r < 4; ++r)
          mx = fmaxf(mx, s[kt4][qf][r]);
      mx = fmaxf(mx, __shfl_xor(mx, 16, 64));
      mx = fmaxf(mx, __shfl_xor(mx, 32, 64));

      const float mo = m_[qf];
      const bool skip = __all(mx <= mo + 8.0f);   // defer-max (T13)
      const float mn = skip ? mo : fmaxf(mo, mx);

      float rs = 0.f;
      _Float16* prow = Pw + (qf * 16 + c) * 72;
      #pragma unroll
      for (int kt4 = 0; kt4 < 4; ++kt4) {
        float p0 = __builtin_amdgcn_exp2f((s[kt4][qf][0] - mn) * 1.44269504f);
        float p1 = __builtin_amdgcn_exp2f((s[kt4][qf][1] - mn) * 1.44269504f);
        float p2 = __builtin_amdgcn_exp2f((s[kt4][qf][2] - mn) * 1.44269504f);
        float p3 = __builtin_amdgcn_exp2f((s[kt4][qf][3] - mn) * 1.44269504f);
        rs += (p0 + p1) + (p2 + p3);
        half4 hp;
        hp[0] = (_Float16)p0; hp[1] = (_Float16)p1;
        hp[2] = (_Float16)p2; hp[3] = (_Float16)p3;
        *(half4*)(prow + kt4 * 16 + g * 4) = hp;   // packed b64, q-row local
      }
      rs += __shfl_xor(rs, 16, 64);
      rs += __shfl_xor(rs, 32, 64);

      if (!skip) {
        const float cor = __builtin_amdgcn_exp2f((mo - mn) * 1.44269504f);
        l_[qf] = l_[qf] * cor + rs;
        m_[qf] = mn;
        // o rows are q = qf*16 + g*4 + r; fetch cor for that q (lane c = g*4+r)
        #pragma unroll
        for (int r = 0; r < 4; ++r) {
          const float corr = __shfl(cor, g * 4 + r, 64);
          #pragma unroll
          for (int dt = 0; dt < 4; ++dt)
            o[qf][dt][r] *= corr;
        }
      } else {
        l_[qf] += rs;
      }
    }

    // PV: O[q][d] += P[q][k] * V[k][d];  A = P rows (q), B = V^T rows (d)
    #pragma unroll
    for (int kk = 0; kk < 2; ++kk) {
      half8 ap0 = *(const half8*)(Pw + (0  + c) * 72 + kk * 32 + g * 8);
      half8 ap1 = *(const half8*)(Pw + (16 + c) * 72 + kk * 32 + g * 8);
      #pragma unroll
      for (int dt = 0; dt < 4; ++dt) {
        half8 bv = *(const half8*)(Vs + (dt * 16 + c) * 72 + kk * 32 + g * 8);
        o[0][dt] = mfma16(ap0, bv, o[0][dt]);
        o[1][dt] = mfma16(ap1, bv, o[1][dt]);
      }
    }
    __syncthreads();
  }

  const int b = bh >> 4, h = bh & 15;
  #pragma unroll
  for (int qt = 0; qt < 2; ++qt) {
    #pragma unroll
    for (int r = 0; r < 4; ++r) {
      const float lr = __shfl(l_[qt], g * 4 + r, 64);  // l for q-row g*4+r
      const float rl = __builtin_amdgcn_rcpf(lr);
      const int n = n0 + qt * 16 + g * 4 + r;
      #pragma unroll
      for (int dt = 0; dt < 4; ++dt) {
        aout[((size_t)(b * SEQ + n)) * EMBD + h * HDIM + dt * 16 + c] =
            (_Float16)(o[qt][dt][r] * rl);
      }
    }
  }
}

extern "C" void kernel_launch(void* const* d_in, const int* in_sizes, int n_in,
                              void* d_out, int out_size, void* d_ws, size_t ws_size,
                              hipStream_t stream) {
  const float* x    = (const float*)d_in[0];
  const float* Wqkv = (const float*)d_in[1];
  const float* bqkv = (const float*)d_in[2];
  const float* Wout = (const float*)d_in[3];
  const float* bout = (const float*)d_in[4];
  float* out = (float*)d_out;

  // workspace layout (halves). aout reuses xh (dead after QKV GEMM).
  _Float16* ws    = (_Float16*)d_ws;
  _Float16* xh    = ws;                                   // 8M
  _Float16* wqkvt = xh + (size_t)MTOT * EMBD;             // 3M
  _Float16* woutt = wqkvt + (size_t)3 * EMBD * EMBD;      // 1M
  _Float16* qbuf  = woutt + (size_t)EMBD * EMBD;          // 8M
  _Float16* kbuf  = qbuf + (size_t)MTOT * EMBD;           // 8M
  _Float16* vtbuf = kbuf + (size_t)MTOT * EMBD;           // 8M
  _Float16* aout  = xh;

  k_cvt<<<4096, 256, 0, stream>>>(x, xh);
  k_transpose<<<dim3(48, 16), 256, 0, stream>>>(Wqkv, wqkvt, 1024, 3072);
  k_transpose<<<dim3(16, 16), 256, 0, stream>>>(Wout, woutt, 1024, 1024);
  k_gemm<0><<<dim3(24, 64), 256, 0, stream>>>(xh, wqkvt, bqkv, nullptr,
                                              qbuf, kbuf, vtbuf);
  k_attn<<<dim3(SEQ / 128, 64), 256, 0, stream>>>(qbuf, kbuf, vtbuf, aout);
  k_gemm<1><<<dim3(8, 64), 256, 0, stream>>>(aout, woutt, bout, out,
                                             nullptr, nullptr, nullptr);
}

// Round 4
// 246.571 us; speedup vs baseline: 1.8516x; 1.0811x over previous
//
#include <hip/hip_runtime.h>

#define SEQ   2048
#define EMBD  1024
#define HEADS 16
#define HDIM  64
#define MTOT  8192
#define LOG2E 1.44269504f

typedef __attribute__((ext_vector_type(8))) _Float16 half8;
typedef __attribute__((ext_vector_type(4))) _Float16 half4;
typedef __attribute__((ext_vector_type(2))) __fp16 fp16x2;
typedef __attribute__((ext_vector_type(4))) float f32x4;

__device__ __forceinline__ f32x4 mfma16(half8 a, half8 b, f32x4 c) {
  return __builtin_amdgcn_mfma_f32_16x16x32_f16(a, b, c, 0, 0, 0);
}

__device__ __forceinline__ void gload_lds16(const void* g, void* l) {
  __builtin_amdgcn_global_load_lds(
      (const __attribute__((address_space(1))) unsigned int*)g,
      (__attribute__((address_space(3))) unsigned int*)l, 16, 0, 0);
}

// ---------------- cast fp32 -> fp16, 8 elems/thread ----------------
__global__ void k_cvt(const float* __restrict__ in, _Float16* __restrict__ out) {
  size_t i = (size_t)blockIdx.x * blockDim.x + threadIdx.x;
  const f32x4* in4 = (const f32x4*)in;
  f32x4 a = in4[2 * i], b = in4[2 * i + 1];
  half8 h;
  h[0] = (_Float16)a[0]; h[1] = (_Float16)a[1];
  h[2] = (_Float16)a[2]; h[3] = (_Float16)a[3];
  h[4] = (_Float16)b[0]; h[5] = (_Float16)b[1];
  h[6] = (_Float16)b[2]; h[7] = (_Float16)b[3];
  *(half8*)(out + i * 8) = h;
}

// ------- LDS-tiled transpose fp32 [R][C] -> fp16 [C][R], 64x64 tiles -------
__global__ __launch_bounds__(256) void k_transpose(const float* __restrict__ in,
                                                   _Float16* __restrict__ out,
                                                   int R, int C) {
  __shared__ _Float16 tile[64][65];
  const int tid = threadIdx.x;
  const int r0 = blockIdx.y * 64, c0 = blockIdx.x * 64;
  const int tr = tid >> 6;   // 0..3
  const int tc = tid & 63;
  #pragma unroll
  for (int i = 0; i < 16; ++i) {
    const int r = i * 4 + tr;
    tile[r][tc] = (_Float16)in[(size_t)(r0 + r) * C + c0 + tc];
  }
  __syncthreads();
  #pragma unroll
  for (int i = 0; i < 16; ++i) {
    const int cc = i * 4 + tr;            // column of in = row of out
    out[(size_t)(c0 + cc) * R + r0 + tc] = tile[tc][cc];  // coalesced in tc
  }
}

// ------- GEMM: C[M,N] = A[M,1024] @ Bt[N,1024]^T + bias -------
// 128x128 tile, BK=64, 4 waves of 64x64, global_load_lds staging.
// EPI 0: scatter f16 to q/k (row-major per head) and vt (transposed per head).
// EPI 1: fp32 + bias to outf.
template<int EPI>
__global__ __launch_bounds__(256) void k_gemm(
    const _Float16* __restrict__ A, const _Float16* __restrict__ Bt,
    const float* __restrict__ bias, float* __restrict__ outf,
    _Float16* __restrict__ q, _Float16* __restrict__ k, _Float16* __restrict__ vt)
{
  __shared__ _Float16 sm[2 * 128 * 64];
  _Float16* sA = sm;
  _Float16* sB = sm + 128 * 64;
  const int tid = threadIdx.x;
  const int l = tid & 63, g = l >> 4, c = l & 15;
  const int w = tid >> 6;
  const int wm = (w >> 1) * 64, wn = (w & 1) * 64;
  const int rowBase = blockIdx.y * 128;
  const int colBase = blockIdx.x * 128;

  f32x4 acc[4][4] = {};

  const _Float16* Ag = A + (size_t)(rowBase + (tid >> 3)) * 1024 + (tid & 7) * 8;
  const _Float16* Bg = Bt + (size_t)(colBase + (tid >> 3)) * 1024 + (tid & 7) * 8;
  _Float16* la = sA + tid * 8;
  _Float16* lb = sB + tid * 8;

  for (int kt = 0; kt < 16; ++kt) {
    const _Float16* ag = Ag + kt * 64;
    const _Float16* bg = Bg + kt * 64;
    #pragma unroll
    for (int i = 0; i < 4; ++i) {
      gload_lds16(ag + (size_t)i * 32 * 1024, la + i * 256 * 8);
      gload_lds16(bg + (size_t)i * 32 * 1024, lb + i * 256 * 8);
    }
    __syncthreads();
    #pragma unroll
    for (int kk = 0; kk < 2; ++kk) {
      half8 af[4], bf[4];
      #pragma unroll
      for (int t = 0; t < 4; ++t)
        af[t] = *(const half8*)(sA + (wm + t * 16 + c) * 64 + kk * 32 + g * 8);
      #pragma unroll
      for (int t = 0; t < 4; ++t)
        bf[t] = *(const half8*)(sB + (wn + t * 16 + c) * 64 + kk * 32 + g * 8);
      #pragma unroll
      for (int mt = 0; mt < 4; ++mt)
        #pragma unroll
        for (int nt = 0; nt < 4; ++nt)
          acc[mt][nt] = mfma16(af[mt], bf[nt], acc[mt][nt]);
    }
    __syncthreads();
  }

  #pragma unroll
  for (int mt = 0; mt < 4; ++mt) {
    #pragma unroll
    for (int nt = 0; nt < 4; ++nt) {
      const int col = colBase + wn + nt * 16 + c;
      const float bv = bias[col];
      #pragma unroll
      for (int r = 0; r < 4; ++r) {
        const int row = rowBase + wm + mt * 16 + g * 4 + r;
        const float val = acc[mt][nt][r] + bv;
        if constexpr (EPI == 0) {
          const int s = col >> 10, h = (col >> 6) & 15, d = col & 63;
          const int b = row >> 11, n = row & 2047;
          const int bh = b * HEADS + h;
          const _Float16 hv = (_Float16)val;
          if (s == 2)      vt[((size_t)bh * HDIM + d) * SEQ + n] = hv;
          else if (s == 1) k [((size_t)bh * SEQ + n) * HDIM + d] = hv;
          else             q [((size_t)bh * SEQ + n) * HDIM + d] = hv;
        } else {
          outf[(size_t)row * EMBD + col] = val;
        }
      }
    }
  }
}

// ---------------- flash attention fwd ----------------
// Swapped QK^T + in-register softmax + T14 async staging + fast skip path.
// grid (SEQ/128, B*H). 4 waves x 32 q-rows. KB=64 keys/iter.
// S^T = mfma(K, Q): lane (g,c) holds S[q = qf*16+c][k = kt4*16+g*4+r].
__global__ __launch_bounds__(256) void k_attn(
    const _Float16* __restrict__ q, const _Float16* __restrict__ kg,
    const _Float16* __restrict__ vt, _Float16* __restrict__ aout)
{
  __shared__ _Float16 sm[(64 + 64 + 4 * 32) * 72];
  _Float16* Ks = sm;                       // [64 keys][72] rows = K[key][d]
  _Float16* Vs = sm + 64 * 72;             // [64 d][72]    rows = V^T[d][key]
  const int tid = threadIdx.x;
  const int w = tid >> 6, l = tid & 63, g = l >> 4, c = l & 15;
  _Float16* Pw = sm + 2 * 64 * 72 + w * 32 * 72;   // per-wave P[q 0..31][72]
  const int bh = blockIdx.y;
  const int n0 = blockIdx.x * 128 + w * 32;
  const _Float16* qb = q  + (size_t)bh * SEQ * HDIM;
  const _Float16* kb = kg + (size_t)bh * SEQ * HDIM;
  const _Float16* vb = vt + (size_t)bh * HDIM * SEQ;
  const int row0 = tid >> 3, cb = tid & 7;

  // Q fragments (B operand), prescaled by 1/sqrt(64) = 1/8 (exact in f16)
  half8 aq[2][2];
  #pragma unroll
  for (int qt = 0; qt < 2; ++qt)
    #pragma unroll
    for (int kk = 0; kk < 2; ++kk) {
      half8 t = *(const half8*)(qb + (size_t)(n0 + qt * 16 + c) * HDIM + kk * 32 + g * 8);
      aq[qt][kk] = t * (_Float16)0.125f;
    }

  float m_[2] = {-1e30f, -1e30f};   // running max for q-row qf*16 + c (g-uniform)
  float l_[2] = {0.f, 0.f};         // per-lane PARTIAL sum (combined in epilogue)
  f32x4 o[2][4] = {};

  // T14 prologue: tile 0 into registers
  half8 kr[2], vr[2];
  #pragma unroll
  for (int i = 0; i < 2; ++i) {
    kr[i] = *(const half8*)(kb + (size_t)(i * 256 + tid) * 8);
    vr[i] = *(const half8*)(vb + (size_t)(i * 32 + row0) * SEQ + cb * 8);
  }

  for (int kt = 0; kt < SEQ / 64; ++kt) {
    __syncthreads();                 // WAR: all waves done reading prev tile
    #pragma unroll
    for (int i = 0; i < 2; ++i) {
      const int row = i * 32 + row0;
      *(half8*)(Ks + row * 72 + cb * 8) = kr[i];
      *(half8*)(Vs + row * 72 + cb * 8) = vr[i];
    }
    if (kt + 1 < SEQ / 64) {         // issue next tile; latency hides under compute
      const _Float16* ksn = kb + (size_t)(kt + 1) * 64 * HDIM;
      #pragma unroll
      for (int i = 0; i < 2; ++i) {
        kr[i] = *(const half8*)(ksn + (size_t)(i * 256 + tid) * 8);
        vr[i] = *(const half8*)(vb + (size_t)(i * 32 + row0) * SEQ + (kt + 1) * 64 + cb * 8);
      }
    }
    __syncthreads();                 // staging visible

    // S^T[k][q]: s[kt4][qf], lane (g,c): k = kt4*16+g*4+r, q = qf*16+c
    f32x4 s[4][2] = {};
    __builtin_amdgcn_s_setprio(1);
    #pragma unroll
    for (int kk = 0; kk < 2; ++kk) {
      #pragma unroll
      for (int kt4 = 0; kt4 < 4; ++kt4) {
        half8 ak = *(const half8*)(Ks + (kt4 * 16 + c) * 72 + kk * 32 + g * 8);
        s[kt4][0] = mfma16(ak, aq[0][kk], s[kt4][0]);
        s[kt4][1] = mfma16(ak, aq[1][kk], s[kt4][1]);
      }
    }
    __builtin_amdgcn_s_setprio(0);

    #pragma unroll
    for (int qf = 0; qf < 2; ++qf) {
      // local (16-value) max; full row max only on the slow path
      float mx = s[0][qf][0];
      #pragma unroll
      for (int kt4 = 0; kt4 < 4; ++kt4)
        #pragma unroll
        for (int r = 0; r < 4; ++r)
          mx = fmaxf(mx, s[kt4][qf][r]);

      if (__any(mx > m_[qf] + 8.0f)) {        // slow path: new max somewhere
        float fm = fmaxf(mx, __shfl_xor(mx, 16, 64));
        fm = fmaxf(fm, __shfl_xor(fm, 32, 64));
        const float mo = m_[qf];
        const float mn = fmaxf(mo, fm);
        const float cor = __builtin_amdgcn_exp2f((mo - mn) * LOG2E);
        m_[qf] = mn;
        l_[qf] *= cor;                        // per-lane partial, cor g-uniform
        #pragma unroll
        for (int r = 0; r < 4; ++r) {         // o rows are q = qf*16 + g*4 + r
          const float corr = __shfl(cor, g * 4 + r, 64);
          #pragma unroll
          for (int dt = 0; dt < 4; ++dt)
            o[qf][dt][r] *= corr;
        }
      }
      const float mn = m_[qf];

      float rs = 0.f;
      _Float16* prow = Pw + (qf * 16 + c) * 72;
      #pragma unroll
      for (int kt4 = 0; kt4 < 4; ++kt4) {
        float p0 = __builtin_amdgcn_exp2f((s[kt4][qf][0] - mn) * LOG2E);
        float p1 = __builtin_amdgcn_exp2f((s[kt4][qf][1] - mn) * LOG2E);
        float p2 = __builtin_amdgcn_exp2f((s[kt4][qf][2] - mn) * LOG2E);
        float p3 = __builtin_amdgcn_exp2f((s[kt4][qf][3] - mn) * LOG2E);
        rs += (p0 + p1) + (p2 + p3);
        union { fp16x2 v2[2]; half4 v4; } u;
        u.v2[0] = __builtin_amdgcn_cvt_pkrtz(p0, p1);
        u.v2[1] = __builtin_amdgcn_cvt_pkrtz(p2, p3);
        *(half4*)(prow + kt4 * 16 + g * 4) = u.v4;   // packed b64, q-row local
      }
      l_[qf] += rs;                           // per-lane partial sum
    }

    // PV: O[q][d] += P[q][k] * V[k][d];  A = P rows (q), B = V^T rows (d)
    __builtin_amdgcn_s_setprio(1);
    #pragma unroll
    for (int kk = 0; kk < 2; ++kk) {
      half8 ap0 = *(const half8*)(Pw + (0  + c) * 72 + kk * 32 + g * 8);
      half8 ap1 = *(const half8*)(Pw + (16 + c) * 72 + kk * 32 + g * 8);
      #pragma unroll
      for (int dt = 0; dt < 4; ++dt) {
        half8 bv = *(const half8*)(Vs + (dt * 16 + c) * 72 + kk * 32 + g * 8);
        o[0][dt] = mfma16(ap0, bv, o[0][dt]);
        o[1][dt] = mfma16(ap1, bv, o[1][dt]);
      }
    }
    __builtin_amdgcn_s_setprio(0);
  }

  const int b = bh >> 4, h = bh & 15;
  #pragma unroll
  for (int qt = 0; qt < 2; ++qt) {
    float lt = l_[qt];                        // combine per-lane partials
    lt += __shfl_xor(lt, 16, 64);
    lt += __shfl_xor(lt, 32, 64);
    #pragma unroll
    for (int r = 0; r < 4; ++r) {
      const float lr = __shfl(lt, g * 4 + r, 64);  // l for q-row g*4+r
      const float rl = __builtin_amdgcn_rcpf(lr);
      const int n = n0 + qt * 16 + g * 4 + r;
      #pragma unroll
      for (int dt = 0; dt < 4; ++dt) {
        aout[((size_t)(b * SEQ + n)) * EMBD + h * HDIM + dt * 16 + c] =
            (_Float16)(o[qt][dt][r] * rl);
      }
    }
  }
}

extern "C" void kernel_launch(void* const* d_in, const int* in_sizes, int n_in,
                              void* d_out, int out_size, void* d_ws, size_t ws_size,
                              hipStream_t stream) {
  const float* x    = (const float*)d_in[0];
  const float* Wqkv = (const float*)d_in[1];
  const float* bqkv = (const float*)d_in[2];
  const float* Wout = (const float*)d_in[3];
  const float* bout = (const float*)d_in[4];
  float* out = (float*)d_out;

  // workspace layout (halves). aout reuses xh (dead after QKV GEMM).
  _Float16* ws    = (_Float16*)d_ws;
  _Float16* xh    = ws;                                   // 8M
  _Float16* wqkvt = xh + (size_t)MTOT * EMBD;             // 3M
  _Float16* woutt = wqkvt + (size_t)3 * EMBD * EMBD;      // 1M
  _Float16* qbuf  = woutt + (size_t)EMBD * EMBD;          // 8M
  _Float16* kbuf  = qbuf + (size_t)MTOT * EMBD;           // 8M
  _Float16* vtbuf = kbuf + (size_t)MTOT * EMBD;           // 8M
  _Float16* aout  = xh;

  k_cvt<<<4096, 256, 0, stream>>>(x, xh);
  k_transpose<<<dim3(48, 16), 256, 0, stream>>>(Wqkv, wqkvt, 1024, 3072);
  k_transpose<<<dim3(16, 16), 256, 0, stream>>>(Wout, woutt, 1024, 1024);
  k_gemm<0><<<dim3(24, 64), 256, 0, stream>>>(xh, wqkvt, bqkv, nullptr,
                                              qbuf, kbuf, vtbuf);
  k_attn<<<dim3(SEQ / 128, 64), 256, 0, stream>>>(qbuf, kbuf, vtbuf, aout);
  k_gemm<1><<<dim3(8, 64), 256, 0, stream>>>(aout, woutt, bout, out,
                                             nullptr, nullptr, nullptr);
}

// Round 5
// 242.057 us; speedup vs baseline: 1.8861x; 1.0186x over previous
//
#include <hip/hip_runtime.h>

#define SEQ   2048
#define EMBD  1024
#define HEADS 16
#define HDIM  64
#define MTOT  8192
#define LOG2E 1.44269504f

typedef __attribute__((ext_vector_type(8))) _Float16 half8;
typedef __attribute__((ext_vector_type(4))) _Float16 half4;
typedef __attribute__((ext_vector_type(2))) __fp16 fp16x2;
typedef __attribute__((ext_vector_type(4))) float f32x4;

__device__ __forceinline__ f32x4 mfma16(half8 a, half8 b, f32x4 c) {
  return __builtin_amdgcn_mfma_f32_16x16x32_f16(a, b, c, 0, 0, 0);
}

__device__ __forceinline__ void gload_lds16(const void* g, void* l) {
  __builtin_amdgcn_global_load_lds(
      (const __attribute__((address_space(1))) unsigned int*)g,
      (__attribute__((address_space(3))) unsigned int*)l, 16, 0, 0);
}

// ---------------- cast fp32 -> fp16, 8 elems/thread ----------------
__global__ void k_cvt(const float* __restrict__ in, _Float16* __restrict__ out) {
  size_t i = (size_t)blockIdx.x * blockDim.x + threadIdx.x;
  const f32x4* in4 = (const f32x4*)in;
  f32x4 a = in4[2 * i], b = in4[2 * i + 1];
  half8 h;
  h[0] = (_Float16)a[0]; h[1] = (_Float16)a[1];
  h[2] = (_Float16)a[2]; h[3] = (_Float16)a[3];
  h[4] = (_Float16)b[0]; h[5] = (_Float16)b[1];
  h[6] = (_Float16)b[2]; h[7] = (_Float16)b[3];
  *(half8*)(out + i * 8) = h;
}

// ------- LDS-tiled transpose fp32 [R][C] -> fp16 [C][R], 64x64 tiles -------
__global__ __launch_bounds__(256) void k_transpose(const float* __restrict__ in,
                                                   _Float16* __restrict__ out,
                                                   int R, int C) {
  __shared__ _Float16 tile[64][65];
  const int tid = threadIdx.x;
  const int r0 = blockIdx.y * 64, c0 = blockIdx.x * 64;
  const int tr = tid >> 6;   // 0..3
  const int tc = tid & 63;
  #pragma unroll
  for (int i = 0; i < 16; ++i) {
    const int r = i * 4 + tr;
    tile[r][tc] = (_Float16)in[(size_t)(r0 + r) * C + c0 + tc];
  }
  __syncthreads();
  #pragma unroll
  for (int i = 0; i < 16; ++i) {
    const int cc = i * 4 + tr;            // column of in = row of out
    out[(size_t)(c0 + cc) * R + r0 + tc] = tile[tc][cc];  // coalesced in tc
  }
}

// ------- GEMM: C[M,N] = A[M,1024] @ Bt[N,1024]^T + bias -------
// 128x128 tile, BK=64, 4 waves of 64x64, global_load_lds staging.
// EPI 0: scatter f16 to q/k (row-major per head) and vt (transposed per head).
// EPI 1: fp32 + bias to outf.
template<int EPI>
__global__ __launch_bounds__(256) void k_gemm(
    const _Float16* __restrict__ A, const _Float16* __restrict__ Bt,
    const float* __restrict__ bias, float* __restrict__ outf,
    _Float16* __restrict__ q, _Float16* __restrict__ k, _Float16* __restrict__ vt)
{
  __shared__ _Float16 sm[2 * 128 * 64];
  _Float16* sA = sm;
  _Float16* sB = sm + 128 * 64;
  const int tid = threadIdx.x;
  const int l = tid & 63, g = l >> 4, c = l & 15;
  const int w = tid >> 6;
  const int wm = (w >> 1) * 64, wn = (w & 1) * 64;
  const int rowBase = blockIdx.y * 128;
  const int colBase = blockIdx.x * 128;

  f32x4 acc[4][4] = {};

  const _Float16* Ag = A + (size_t)(rowBase + (tid >> 3)) * 1024 + (tid & 7) * 8;
  const _Float16* Bg = Bt + (size_t)(colBase + (tid >> 3)) * 1024 + (tid & 7) * 8;
  _Float16* la = sA + tid * 8;
  _Float16* lb = sB + tid * 8;

  for (int kt = 0; kt < 16; ++kt) {
    const _Float16* ag = Ag + kt * 64;
    const _Float16* bg = Bg + kt * 64;
    #pragma unroll
    for (int i = 0; i < 4; ++i) {
      gload_lds16(ag + (size_t)i * 32 * 1024, la + i * 256 * 8);
      gload_lds16(bg + (size_t)i * 32 * 1024, lb + i * 256 * 8);
    }
    __syncthreads();
    #pragma unroll
    for (int kk = 0; kk < 2; ++kk) {
      half8 af[4], bf[4];
      #pragma unroll
      for (int t = 0; t < 4; ++t)
        af[t] = *(const half8*)(sA + (wm + t * 16 + c) * 64 + kk * 32 + g * 8);
      #pragma unroll
      for (int t = 0; t < 4; ++t)
        bf[t] = *(const half8*)(sB + (wn + t * 16 + c) * 64 + kk * 32 + g * 8);
      #pragma unroll
      for (int mt = 0; mt < 4; ++mt)
        #pragma unroll
        for (int nt = 0; nt < 4; ++nt)
          acc[mt][nt] = mfma16(af[mt], bf[nt], acc[mt][nt]);
    }
    __syncthreads();
  }

  #pragma unroll
  for (int mt = 0; mt < 4; ++mt) {
    #pragma unroll
    for (int nt = 0; nt < 4; ++nt) {
      const int col = colBase + wn + nt * 16 + c;
      const float bv = bias[col];
      #pragma unroll
      for (int r = 0; r < 4; ++r) {
        const int row = rowBase + wm + mt * 16 + g * 4 + r;
        const float val = acc[mt][nt][r] + bv;
        if constexpr (EPI == 0) {
          const int s = col >> 10, h = (col >> 6) & 15, d = col & 63;
          const int b = row >> 11, n = row & 2047;
          const int bh = b * HEADS + h;
          const _Float16 hv = (_Float16)val;
          if (s == 2)      vt[((size_t)bh * HDIM + d) * SEQ + n] = hv;
          else if (s == 1) k [((size_t)bh * SEQ + n) * HDIM + d] = hv;
          else             q [((size_t)bh * SEQ + n) * HDIM + d] = hv;
        } else {
          outf[(size_t)row * EMBD + col] = val;
        }
      }
    }
  }
}

// ---------------- flash attention fwd ----------------
// 8 waves x 32 q-rows = 256 q-rows/block; KVBLK=64. Swapped QK^T,
// in-register softmax, T14 async staging, fast skip, T1 XCD swizzle.
// S^T = mfma(K, Q): lane (g,c) holds S[q = qf*16+c][k = kt4*16+g*4+r].
__global__ __launch_bounds__(512) void k_attn(
    const _Float16* __restrict__ q, const _Float16* __restrict__ kg,
    const _Float16* __restrict__ vt, _Float16* __restrict__ aout)
{
  __shared__ _Float16 sm[(64 + 64 + 8 * 32) * 72];
  _Float16* Ks = sm;                       // [64 keys][72] rows = K[key][d]
  _Float16* Vs = sm + 64 * 72;             // [64 d][72]    rows = V^T[d][key]
  const int tid = threadIdx.x;
  const int w = tid >> 6, l = tid & 63, g = l >> 4, c = l & 15;
  _Float16* Pw = sm + 2 * 64 * 72 + w * 32 * 72;   // per-wave P[q 0..31][72]

  // XCD-chunked bijective swizzle (512 blocks, 8 XCDs -> 64 contiguous each)
  const int orig = blockIdx.x;
  const int lb = (orig & 7) * 64 + (orig >> 3);
  const int bh = lb >> 3;                  // 8 q-tiles per bh
  const int n0 = (lb & 7) * 256 + w * 32;

  const _Float16* qb = q  + (size_t)bh * SEQ * HDIM;
  const _Float16* kb = kg + (size_t)bh * SEQ * HDIM;
  const _Float16* vb = vt + (size_t)bh * HDIM * SEQ;
  const int row0 = tid >> 3, cb = tid & 7;

  // Q fragments (B operand), prescaled by 1/sqrt(64) = 1/8 (exact in f16)
  half8 aq[2][2];
  #pragma unroll
  for (int qt = 0; qt < 2; ++qt)
    #pragma unroll
    for (int kk = 0; kk < 2; ++kk) {
      half8 t = *(const half8*)(qb + (size_t)(n0 + qt * 16 + c) * HDIM + kk * 32 + g * 8);
      aq[qt][kk] = t * (_Float16)0.125f;
    }

  float m_[2] = {-1e30f, -1e30f};   // running max for q-row qf*16 + c (g-uniform)
  float l_[2] = {0.f, 0.f};         // per-lane PARTIAL sum (combined in epilogue)
  f32x4 o[2][4] = {};

  // T14 prologue: tile 0 into registers (1 half8/thread for K and V each)
  half8 kr = *(const half8*)(kb + (size_t)tid * 8);
  half8 vr = *(const half8*)(vb + (size_t)row0 * SEQ + cb * 8);

  for (int kt = 0; kt < SEQ / 64; ++kt) {
    __syncthreads();                 // WAR: all waves done reading prev tile
    *(half8*)(Ks + row0 * 72 + cb * 8) = kr;
    *(half8*)(Vs + row0 * 72 + cb * 8) = vr;
    if (kt + 1 < SEQ / 64) {         // issue next tile; latency hides under compute
      kr = *(const half8*)(kb + (size_t)(kt + 1) * 64 * HDIM + (size_t)tid * 8);
      vr = *(const half8*)(vb + (size_t)row0 * SEQ + (kt + 1) * 64 + cb * 8);
    }
    __syncthreads();                 // staging visible

    // S^T[k][q]: s[kt4][qf], lane (g,c): k = kt4*16+g*4+r, q = qf*16+c
    f32x4 s[4][2] = {};
    __builtin_amdgcn_s_setprio(1);
    #pragma unroll
    for (int kk = 0; kk < 2; ++kk) {
      #pragma unroll
      for (int kt4 = 0; kt4 < 4; ++kt4) {
        half8 ak = *(const half8*)(Ks + (kt4 * 16 + c) * 72 + kk * 32 + g * 8);
        s[kt4][0] = mfma16(ak, aq[0][kk], s[kt4][0]);
        s[kt4][1] = mfma16(ak, aq[1][kk], s[kt4][1]);
      }
    }
    __builtin_amdgcn_s_setprio(0);

    #pragma unroll
    for (int qf = 0; qf < 2; ++qf) {
      // local (16-value) max; full row max only on the slow path
      float mx = s[0][qf][0];
      #pragma unroll
      for (int kt4 = 0; kt4 < 4; ++kt4)
        #pragma unroll
        for (int r = 0; r < 4; ++r)
          mx = fmaxf(mx, s[kt4][qf][r]);

      if (__any(mx > m_[qf] + 8.0f)) {        // slow path: new max somewhere
        float fm = fmaxf(mx, __shfl_xor(mx, 16, 64));
        fm = fmaxf(fm, __shfl_xor(fm, 32, 64));
        const float mo = m_[qf];
        const float mn = fmaxf(mo, fm);
        const float cor = __builtin_amdgcn_exp2f((mo - mn) * LOG2E);
        m_[qf] = mn;
        l_[qf] *= cor;                        // per-lane partial, cor g-uniform
        #pragma unroll
        for (int r = 0; r < 4; ++r) {         // o rows are q = qf*16 + g*4 + r
          const float corr = __shfl(cor, g * 4 + r, 64);
          #pragma unroll
          for (int dt = 0; dt < 4; ++dt)
            o[qf][dt][r] *= corr;
        }
      }
      const float mn = m_[qf];

      float rs = 0.f;
      _Float16* prow = Pw + (qf * 16 + c) * 72;
      #pragma unroll
      for (int kt4 = 0; kt4 < 4; ++kt4) {
        float p0 = __builtin_amdgcn_exp2f((s[kt4][qf][0] - mn) * LOG2E);
        float p1 = __builtin_amdgcn_exp2f((s[kt4][qf][1] - mn) * LOG2E);
        float p2 = __builtin_amdgcn_exp2f((s[kt4][qf][2] - mn) * LOG2E);
        float p3 = __builtin_amdgcn_exp2f((s[kt4][qf][3] - mn) * LOG2E);
        rs += (p0 + p1) + (p2 + p3);
        union { fp16x2 v2[2]; half4 v4; } u;
        u.v2[0] = __builtin_amdgcn_cvt_pkrtz(p0, p1);
        u.v2[1] = __builtin_amdgcn_cvt_pkrtz(p2, p3);
        *(half4*)(prow + kt4 * 16 + g * 4) = u.v4;   // packed b64, q-row local
      }
      l_[qf] += rs;                           // per-lane partial sum
    }

    // PV: O[q][d] += P[q][k] * V[k][d];  A = P rows (q), B = V^T rows (d)
    __builtin_amdgcn_s_setprio(1);
    #pragma unroll
    for (int kk = 0; kk < 2; ++kk) {
      half8 ap0 = *(const half8*)(Pw + (0  + c) * 72 + kk * 32 + g * 8);
      half8 ap1 = *(const half8*)(Pw + (16 + c) * 72 + kk * 32 + g * 8);
      #pragma unroll
      for (int dt = 0; dt < 4; ++dt) {
        half8 bv = *(const half8*)(Vs + (dt * 16 + c) * 72 + kk * 32 + g * 8);
        o[0][dt] = mfma16(ap0, bv, o[0][dt]);
        o[1][dt] = mfma16(ap1, bv, o[1][dt]);
      }
    }
    __builtin_amdgcn_s_setprio(0);
  }

  const int b = bh >> 4, h = bh & 15;
  #pragma unroll
  for (int qt = 0; qt < 2; ++qt) {
    float lt = l_[qt];                        // combine per-lane partials
    lt += __shfl_xor(lt, 16, 64);
    lt += __shfl_xor(lt, 32, 64);
    #pragma unroll
    for (int r = 0; r < 4; ++r) {
      const float lr = __shfl(lt, g * 4 + r, 64);  // l for q-row g*4+r
      const float rl = __builtin_amdgcn_rcpf(lr);
      const int n = n0 + qt * 16 + g * 4 + r;
      #pragma unroll
      for (int dt = 0; dt < 4; ++dt) {
        aout[((size_t)(b * SEQ + n)) * EMBD + h * HDIM + dt * 16 + c] =
            (_Float16)(o[qt][dt][r] * rl);
      }
    }
  }
}

extern "C" void kernel_launch(void* const* d_in, const int* in_sizes, int n_in,
                              void* d_out, int out_size, void* d_ws, size_t ws_size,
                              hipStream_t stream) {
  const float* x    = (const float*)d_in[0];
  const float* Wqkv = (const float*)d_in[1];
  const float* bqkv = (const float*)d_in[2];
  const float* Wout = (const float*)d_in[3];
  const float* bout = (const float*)d_in[4];
  float* out = (float*)d_out;

  // workspace layout (halves). aout reuses xh (dead after QKV GEMM).
  _Float16* ws    = (_Float16*)d_ws;
  _Float16* xh    = ws;                                   // 8M
  _Float16* wqkvt = xh + (size_t)MTOT * EMBD;             // 3M
  _Float16* woutt = wqkvt + (size_t)3 * EMBD * EMBD;      // 1M
  _Float16* qbuf  = woutt + (size_t)EMBD * EMBD;          // 8M
  _Float16* kbuf  = qbuf + (size_t)MTOT * EMBD;           // 8M
  _Float16* vtbuf = kbuf + (size_t)MTOT * EMBD;           // 8M
  _Float16* aout  = xh;

  k_cvt<<<4096, 256, 0, stream>>>(x, xh);
  k_transpose<<<dim3(48, 16), 256, 0, stream>>>(Wqkv, wqkvt, 1024, 3072);
  k_transpose<<<dim3(16, 16), 256, 0, stream>>>(Wout, woutt, 1024, 1024);
  k_gemm<0><<<dim3(24, 64), 256, 0, stream>>>(xh, wqkvt, bqkv, nullptr,
                                              qbuf, kbuf, vtbuf);
  k_attn<<<512, 512, 0, stream>>>(qbuf, kbuf, vtbuf, aout);
  k_gemm<1><<<dim3(8, 64), 256, 0, stream>>>(aout, woutt, bout, out,
                                             nullptr, nullptr, nullptr);
}